// Round 9
// baseline (262.765 us; speedup 1.0000x reference)
//
#include <hip/hip_runtime.h>
#include <hip/hip_bf16.h>

// DTWLoss: out[b] = softDTW(sqdist(x,y)) - 0.5*(softDTW(sqdist(x,x)) + softDTW(sqdist(y,y)))
// B=64, N=M=512, F=256, gamma=0.1, BIG=1e8. Output: 64 fp32.
//
// TWO dispatches:
// Kernel 1: fused convert+norm+GEMM (round-8 structure) with two fixes:
//           z = 3b+p (concurrent blocks share one batch's fp32 inputs ->
//           L2/L3 resident; round-8's z=p*64+b gave 262MB FETCH) and LDA=34
//           (17-bank odd stride; round-6 measured 0 conflicts vs 6.29M at 40).
// Kernel 2: wavefront DTW with the MIN-PLUS SCAN trick: c_r = P_r+min(G_r,u1)
//           where P_r = prefix-sum(d), G_r = prefix-min(e_r - P_{r-1}) are
//           u1-independent. Inter-lane critical path = shfl + min + add
//           (was shfl + 8 serial cells = 542cyc/step). Branch-free via
//           cndmask. Hardmin (|softmin-min|<=gamma*ln3/cell, <=112 total vs
//           5242.88 threshold). Depth-2 group-8 D prefetch kept.

#define SDTW_BIG   1e8f
#define LDA 34   // LDS row stride in shorts (32 + 2 pad -> 17 banks, odd)

typedef __attribute__((ext_vector_type(8))) short short8;   // 8 bf16
typedef __attribute__((ext_vector_type(4))) float floatx4;  // mfma acc

__device__ __forceinline__ unsigned short f2bf(float f) {
    __hip_bfloat16 h = __float2bfloat16(f);
    return *reinterpret_cast<unsigned short*>(&h);
}
__device__ __forceinline__ float bf2f_lo(unsigned int u) {
    return __uint_as_float(u << 16);
}
__device__ __forceinline__ float bf2f_hi(unsigned int u) {
    return __uint_as_float(u & 0xFFFF0000u);
}

// Convert 8 fp32 -> short8 bf16, accumulating sum-of-squares in fp32.
__device__ __forceinline__ short8 cvt8(const float4 u, const float4 v, float& ss) {
    ss += u.x * u.x + u.y * u.y + u.z * u.z + u.w * u.w
        + v.x * v.x + v.y * v.y + v.z * v.z + v.w * v.w;
    short8 r;
    r[0] = (short)f2bf(u.x); r[1] = (short)f2bf(u.y);
    r[2] = (short)f2bf(u.z); r[3] = (short)f2bf(u.w);
    r[4] = (short)f2bf(v.x); r[5] = (short)f2bf(v.y);
    r[6] = (short)f2bf(v.z); r[7] = (short)f2bf(v.w);
    return r;
}

// ---- Kernel 1: fused convert + norms + GEMM -------------------------------
// grid (4, 4, 192) x 256 threads. z = 3b+p. D bf16 col-major.
__global__ __launch_bounds__(256, 2) void gemm_fused_kernel(
    const float* __restrict__ x, const float* __restrict__ y,
    unsigned short* __restrict__ Dws, float* __restrict__ out) {
    __shared__ short Ab[2][128 * LDA];
    __shared__ short Bb[2][128 * LDA];
    __shared__ float nAs[128];
    __shared__ float nBs[128];

    if (blockIdx.x == 0 && blockIdx.y == 0 && blockIdx.z == 0 && threadIdx.x < 64)
        out[threadIdx.x] = 0.0f;          // replaces the memset dispatch

    const int z = blockIdx.z;            // 3*b + p
    const int b = z / 3;
    const int p = z - 3 * b;
    const float* A  = (p == 2) ? y : x;
    const float* Bm = (p == 1) ? x : y;
    A  += (size_t)b * (512 * 256);
    Bm += (size_t)b * (512 * 256);
    unsigned short* Dmat = Dws + (size_t)z * (512 * 512);

    const int tid  = threadIdx.x;
    const int wave = tid >> 6;
    const int lane = tid & 63;
    const int quad = lane >> 4;
    const int l16  = lane & 15;
    const int wr = wave >> 1, wc = wave & 1;
    const int i0base = blockIdx.x * 128;
    const int j0base = blockIdx.y * 128;

    // Staging: thread tid handles rows srow/srow+64 of A and B, feats
    // [c*32 + sq*8, +8) per chunk c (2 float4 loads per row per chunk).
    const int srow = tid >> 2;
    const int sq   = tid & 3;
    const float4* gA0 = reinterpret_cast<const float4*>(A  + (size_t)(i0base + srow)      * 256) + sq * 2;
    const float4* gA1 = reinterpret_cast<const float4*>(A  + (size_t)(i0base + srow + 64) * 256) + sq * 2;
    const float4* gB0 = reinterpret_cast<const float4*>(Bm + (size_t)(j0base + srow)      * 256) + sq * 2;
    const float4* gB1 = reinterpret_cast<const float4*>(Bm + (size_t)(j0base + srow + 64) * 256) + sq * 2;
    const int lO0 = srow * LDA + sq * 8;
    const int lO1 = (srow + 64) * LDA + sq * 8;

    float ssA0 = 0.f, ssA1 = 0.f, ssB0 = 0.f, ssB1 = 0.f;

    // Preload chunk 0 -> buf 0 (convert + norm at store site).
    {
        float4 a00 = gA0[0], a01 = gA0[1], a10 = gA1[0], a11 = gA1[1];
        float4 b00 = gB0[0], b01 = gB0[1], b10 = gB1[0], b11 = gB1[1];
        *reinterpret_cast<short8*>(&Ab[0][lO0]) = cvt8(a00, a01, ssA0);
        *reinterpret_cast<short8*>(&Ab[0][lO1]) = cvt8(a10, a11, ssA1);
        *reinterpret_cast<short8*>(&Bb[0][lO0]) = cvt8(b00, b01, ssB0);
        *reinterpret_cast<short8*>(&Bb[0][lO1]) = cvt8(b10, b11, ssB1);
    }
    __syncthreads();

    floatx4 acc[4][4];
    #pragma unroll
    for (int mt = 0; mt < 4; ++mt)
        #pragma unroll
        for (int nt = 0; nt < 4; ++nt) acc[mt][nt] = (floatx4){0.f, 0.f, 0.f, 0.f};

    #pragma unroll
    for (int c = 0; c < 8; ++c) {
        const int cb = c & 1;
        float4 a00, a01, a10, a11, b00, b01, b10, b11;
        if (c < 7) {                      // issue next chunk's global loads
            const int fi = (c + 1) * 8;
            a00 = gA0[fi]; a01 = gA0[fi + 1];
            a10 = gA1[fi]; a11 = gA1[fi + 1];
            b00 = gB0[fi]; b01 = gB0[fi + 1];
            b10 = gB1[fi]; b11 = gB1[fi + 1];
        }
        short8 af[4], bfr[4];
        #pragma unroll
        for (int mt = 0; mt < 4; ++mt)
            af[mt] = *reinterpret_cast<const short8*>(&Ab[cb][(wr * 64 + mt * 16 + l16) * LDA + quad * 8]);
        #pragma unroll
        for (int nt = 0; nt < 4; ++nt)
            bfr[nt] = *reinterpret_cast<const short8*>(&Bb[cb][(wc * 64 + nt * 16 + l16) * LDA + quad * 8]);
        #pragma unroll
        for (int mt = 0; mt < 4; ++mt)
            #pragma unroll
            for (int nt = 0; nt < 4; ++nt)
                acc[mt][nt] = __builtin_amdgcn_mfma_f32_16x16x32_bf16(af[mt], bfr[nt], acc[mt][nt], 0, 0, 0);
        if (c < 7) {                      // convert + stage after MFMA burst
            *reinterpret_cast<short8*>(&Ab[1 - cb][lO0]) = cvt8(a00, a01, ssA0);
            *reinterpret_cast<short8*>(&Ab[1 - cb][lO1]) = cvt8(a10, a11, ssA1);
            *reinterpret_cast<short8*>(&Bb[1 - cb][lO0]) = cvt8(b00, b01, ssB0);
            *reinterpret_cast<short8*>(&Bb[1 - cb][lO1]) = cvt8(b10, b11, ssB1);
            __syncthreads();
        }
    }

    // Row-norm reduction across the 4 quarter-lanes (tid bits 0-1).
    ssA0 += __shfl_xor(ssA0, 1); ssA0 += __shfl_xor(ssA0, 2);
    ssA1 += __shfl_xor(ssA1, 1); ssA1 += __shfl_xor(ssA1, 2);
    ssB0 += __shfl_xor(ssB0, 1); ssB0 += __shfl_xor(ssB0, 2);
    ssB1 += __shfl_xor(ssB1, 1); ssB1 += __shfl_xor(ssB1, 2);
    if (sq == 0) {
        nAs[srow] = ssA0; nAs[srow + 64] = ssA1;
        nBs[srow] = ssB0; nBs[srow + 64] = ssB1;
    }
    __syncthreads();

    // Epilogue: C/D layout col=lane&15, row=quad*4+reg (m89-verified).
    #pragma unroll
    for (int mt = 0; mt < 4; ++mt) {
        const int il = wr * 64 + mt * 16 + quad * 4;
        const float4 nv = *reinterpret_cast<const float4*>(&nAs[il]);
        const int ibase = i0base + il;
        #pragma unroll
        for (int nt = 0; nt < 4; ++nt) {
            const int jl = wc * 64 + nt * 16 + l16;
            const float y2 = nBs[jl];
            ushort4 pk;
            pk.x = f2bf(nv.x + y2 - 2.0f * acc[mt][nt][0]);
            pk.y = f2bf(nv.y + y2 - 2.0f * acc[mt][nt][1]);
            pk.z = f2bf(nv.z + y2 - 2.0f * acc[mt][nt][2]);
            pk.w = f2bf(nv.w + y2 - 2.0f * acc[mt][nt][3]);
            *reinterpret_cast<ushort4*>(Dmat + (size_t)(j0base + jl) * 512 + ibase) = pk;
        }
    }
}

// ---- Kernel 2: one-wave hardmin DTW, min-plus scan form -------------------
// grid 192 x 64 threads (one wave). Lane t owns rows [8t, 8t+8).
// Step s: column j = s - t.  c_r = P_r + min(G_r, u1): P_r = prefix-sum(d),
// G_r = prefix-min(e_r - P_{r-1}) are u1-independent, so the inter-lane
// serial path is just shfl -> min -> add -> shfl.
__global__ __launch_bounds__(64, 1) void dtw_wave_kernel(
    const unsigned short* __restrict__ Dws, float* __restrict__ out) {
    const int z = blockIdx.x;            // 3*b + p
    const int b = z / 3;
    const int p = z - 3 * b;
    const unsigned short* Dmat = Dws + (size_t)z * 262144;   // col-major
    const int t = threadIdx.x;           // lane 0..63

    float prev[8];                        // R[8t+r, j-1]
    #pragma unroll
    for (int r = 0; r < 8; ++r) prev[r] = SDTW_BIG;
    float bot = SDTW_BIG;                 // bottom-row value after last step
    float u0s = SDTW_BIG;                 // lane t-1 bottom @ previous column

    const uint4* Dcol = reinterpret_cast<const uint4*>(Dmat) + t;  // + j*64

    uint4 cur[8], nxt[8];
    #pragma unroll
    for (int k = 0; k < 8; ++k) {         // group 0
        const int j0k = k - t;
        const int jc = j0k < 0 ? 0 : (j0k > 511 ? 511 : j0k);
        cur[k] = Dcol[(size_t)jc * 64];
    }
    #pragma unroll
    for (int k = 0; k < 8; ++k) {         // group 1
        const int j1k = 8 + k - t;
        const int jc = j1k < 0 ? 0 : (j1k > 511 ? 511 : j1k);
        nxt[k] = Dcol[(size_t)jc * 64];
    }

    for (int g = 0; g < 72; ++g) {
        const int s0 = g * 8;
        // prefetch group g+2: 16 loads in flight during 2 groups of compute
        uint4 fut[8];
        #pragma unroll
        for (int k = 0; k < 8; ++k) {
            const int jn = s0 + 16 + k - t;
            const int jc = jn < 0 ? 0 : (jn > 511 ? 511 : jn);
            fut[k] = Dcol[(size_t)jc * 64];
        }
        #pragma unroll
        for (int k = 0; k < 8; ++k) {
            const int j = s0 + k - t;
            // issue the cross-lane exchange FIRST; prep overlaps its flight
            const float recv = __shfl_up(bot, 1);

            // ---- u1-independent prep ----
            float d[8];
            d[0] = bf2f_lo(cur[k].x); d[1] = bf2f_hi(cur[k].x);
            d[2] = bf2f_lo(cur[k].y); d[3] = bf2f_hi(cur[k].y);
            d[4] = bf2f_lo(cur[k].z); d[5] = bf2f_hi(cur[k].z);
            d[6] = bf2f_lo(cur[k].w); d[7] = bf2f_hi(cur[k].w);
            float u0 = u0s;
            if (t == 0) { u0 = (j == 0) ? 0.0f : SDTW_BIG; }
            else if (j == 0) { u0 = SDTW_BIG; }
            float e[8];
            e[0] = fminf(u0, prev[0]);
            #pragma unroll
            for (int r = 1; r < 8; ++r) e[r] = fminf(prev[r - 1], prev[r]);
            float P[8];
            P[0] = d[0];
            #pragma unroll
            for (int r = 1; r < 8; ++r) P[r] = P[r - 1] + d[r];
            float G[8];
            G[0] = e[0];                  // H_0 = e_0 - P_{-1}, P_{-1}=0
            #pragma unroll
            for (int r = 1; r < 8; ++r) G[r] = fminf(G[r - 1], e[r] - P[r - 1]);

            // ---- u1 arrives: O(1) on the serial path ----
            float u1 = recv;
            if (t == 0) u1 = SDTW_BIG;
            u0s = u1;                     // next step's u0 (overrides reapplied)
            const bool valid = (j >= 0) && (j < 512);
            #pragma unroll
            for (int r = 0; r < 8; ++r) {
                const float c = P[r] + fminf(G[r], u1);
                prev[r] = valid ? c : SDTW_BIG;
            }
            bot = valid ? (P[7] + fminf(G[7], u1)) : bot;
        }
        #pragma unroll
        for (int k = 0; k < 8; ++k) { cur[k] = nxt[k]; nxt[k] = fut[k]; }
    }

    if (t == 63) {                // bot == R[511,511]
        const float coef = (p == 0) ? 1.0f : -0.5f;
        atomicAdd(&out[b], coef * bot);
    }
}

extern "C" void kernel_launch(void* const* d_in, const int* in_sizes, int n_in,
                              void* d_out, int out_size, void* d_ws, size_t ws_size,
                              hipStream_t stream) {
    const float* x = (const float*)d_in[0];
    const float* y = (const float*)d_in[1];
    float* out = (float*)d_out;

    // ws layout: [0, 100663296) D bf16, 192 matrices x 262144 elems (col-major)
    unsigned short* Dws = (unsigned short*)d_ws;

    gemm_fused_kernel<<<dim3(4, 4, 192), 256, 0, stream>>>(x, y, Dws, out);
    dtw_wave_kernel<<<192, 64, 0, stream>>>(Dws, out);
}

// Round 10
// 248.328 us; speedup vs baseline: 1.0581x; 1.0581x over previous
//
#include <hip/hip_runtime.h>
#include <hip/hip_bf16.h>

// DTWLoss: out[b] = softDTW(sqdist(x,y)) - 0.5*(softDTW(sqdist(x,x)) + softDTW(sqdist(y,y)))
// B=64, N=M=512, F=256, gamma=0.1, BIG=1e8. Output: 64 fp32.
//
// Kernel 1: fused convert+norm+GEMM. Round-8 main loop (LDA=40 — measured
//           fewer conflicts than 34 in this kernel), z=3b+p (L2-shared batch
//           inputs, round-9-verified FETCH win). NEW: LDS-transpose epilogue
//           -> 256B-contiguous stores, killing fetch-on-partial-write
//           (round-9 FETCH 169MB ~= 67 ideal + 98 write-allocate).
// Kernel 2: wavefront DTW (hardmin; |softmin-min|<=gamma*ln3/cell, <=112
//           total vs 5242.88 threshold), ONE WAVE per matrix. NEW: MACRO-STEP
//           form — lane t does an 8x8 tile (rows [8t,8t+8) x one 8-col block)
//           per exchange: 8 pipelined shfls + ONE wait per 64 cells instead
//           of 1 shfl-roundtrip per 8 cells (per-step bpermute latency was
//           the invariant ~550cyc/step across all prior variants).
//           127 macro-steps, depth-2 block prefetch.

#define SDTW_BIG   1e8f
#define LDA 40        // LDS row stride in shorts (32 + 8 pad)
#define ABUF 5120     // 128*LDA shorts per buffer
#define TST 136       // transpose stride in shorts (272B = 17*16B: aligned)

typedef __attribute__((ext_vector_type(8))) short short8;   // 8 bf16
typedef __attribute__((ext_vector_type(4))) float floatx4;  // mfma acc

__device__ __forceinline__ unsigned short f2bf(float f) {
    __hip_bfloat16 h = __float2bfloat16(f);
    return *reinterpret_cast<unsigned short*>(&h);
}
__device__ __forceinline__ float bf2f_lo(unsigned int u) {
    return __uint_as_float(u << 16);
}
__device__ __forceinline__ float bf2f_hi(unsigned int u) {
    return __uint_as_float(u & 0xFFFF0000u);
}

// Convert 8 fp32 -> short8 bf16, accumulating sum-of-squares in fp32.
__device__ __forceinline__ short8 cvt8(const float4 u, const float4 v, float& ss) {
    ss += u.x * u.x + u.y * u.y + u.z * u.z + u.w * u.w
        + v.x * v.x + v.y * v.y + v.z * v.z + v.w * v.w;
    short8 r;
    r[0] = (short)f2bf(u.x); r[1] = (short)f2bf(u.y);
    r[2] = (short)f2bf(u.z); r[3] = (short)f2bf(u.w);
    r[4] = (short)f2bf(v.x); r[5] = (short)f2bf(v.y);
    r[6] = (short)f2bf(v.z); r[7] = (short)f2bf(v.w);
    return r;
}

// ---- Kernel 1: fused convert + norms + GEMM -------------------------------
// grid (4, 4, 192) x 256 threads. z = 3b+p. D bf16 col-major.
__global__ __launch_bounds__(256, 2) void gemm_fused_kernel(
    const float* __restrict__ x, const float* __restrict__ y,
    unsigned short* __restrict__ Dws, float* __restrict__ out) {
    // [0,ABUF) Ab0 | [ABUF,2*ABUF) Ab1 | [2A,3A) Bb0 | [3A,4A) Bb1.
    // Epilogue reuses [0, 128*TST) as the transpose tile T.
    __shared__ __align__(16) short smem[4 * ABUF];
    __shared__ float nAs[128];
    __shared__ float nBs[128];

    if (blockIdx.x == 0 && blockIdx.y == 0 && blockIdx.z == 0 && threadIdx.x < 64)
        out[threadIdx.x] = 0.0f;          // replaces the memset dispatch

    const int z = blockIdx.z;            // 3*b + p
    const int b = z / 3;
    const int p = z - 3 * b;
    const float* A  = (p == 2) ? y : x;
    const float* Bm = (p == 1) ? x : y;
    A  += (size_t)b * (512 * 256);
    Bm += (size_t)b * (512 * 256);
    unsigned short* Dmat = Dws + (size_t)z * (512 * 512);

    const int tid  = threadIdx.x;
    const int wave = tid >> 6;
    const int lane = tid & 63;
    const int quad = lane >> 4;
    const int l16  = lane & 15;
    const int wr = wave >> 1, wc = wave & 1;
    const int i0base = blockIdx.x * 128;
    const int j0base = blockIdx.y * 128;

    const int srow = tid >> 2;
    const int sq   = tid & 3;
    const float4* gA0 = reinterpret_cast<const float4*>(A  + (size_t)(i0base + srow)      * 256) + sq * 2;
    const float4* gA1 = reinterpret_cast<const float4*>(A  + (size_t)(i0base + srow + 64) * 256) + sq * 2;
    const float4* gB0 = reinterpret_cast<const float4*>(Bm + (size_t)(j0base + srow)      * 256) + sq * 2;
    const float4* gB1 = reinterpret_cast<const float4*>(Bm + (size_t)(j0base + srow + 64) * 256) + sq * 2;
    const int lO0 = srow * LDA + sq * 8;
    const int lO1 = (srow + 64) * LDA + sq * 8;

    float ssA0 = 0.f, ssA1 = 0.f, ssB0 = 0.f, ssB1 = 0.f;

    {   // preload chunk 0 -> buf 0
        float4 a00 = gA0[0], a01 = gA0[1], a10 = gA1[0], a11 = gA1[1];
        float4 b00 = gB0[0], b01 = gB0[1], b10 = gB1[0], b11 = gB1[1];
        *reinterpret_cast<short8*>(&smem[0 * ABUF + lO0]) = cvt8(a00, a01, ssA0);
        *reinterpret_cast<short8*>(&smem[0 * ABUF + lO1]) = cvt8(a10, a11, ssA1);
        *reinterpret_cast<short8*>(&smem[2 * ABUF + lO0]) = cvt8(b00, b01, ssB0);
        *reinterpret_cast<short8*>(&smem[2 * ABUF + lO1]) = cvt8(b10, b11, ssB1);
    }
    __syncthreads();

    floatx4 acc[4][4];
    #pragma unroll
    for (int mt = 0; mt < 4; ++mt)
        #pragma unroll
        for (int nt = 0; nt < 4; ++nt) acc[mt][nt] = (floatx4){0.f, 0.f, 0.f, 0.f};

    #pragma unroll
    for (int c = 0; c < 8; ++c) {
        const int cb = c & 1;
        float4 a00, a01, a10, a11, b00, b01, b10, b11;
        if (c < 7) {                      // issue next chunk's global loads
            const int fi = (c + 1) * 8;
            a00 = gA0[fi]; a01 = gA0[fi + 1];
            a10 = gA1[fi]; a11 = gA1[fi + 1];
            b00 = gB0[fi]; b01 = gB0[fi + 1];
            b10 = gB1[fi]; b11 = gB1[fi + 1];
        }
        short8 af[4], bfr[4];
        #pragma unroll
        for (int mt = 0; mt < 4; ++mt)
            af[mt] = *reinterpret_cast<const short8*>(&smem[cb * ABUF + (wr * 64 + mt * 16 + l16) * LDA + quad * 8]);
        #pragma unroll
        for (int nt = 0; nt < 4; ++nt)
            bfr[nt] = *reinterpret_cast<const short8*>(&smem[(2 + cb) * ABUF + (wc * 64 + nt * 16 + l16) * LDA + quad * 8]);
        #pragma unroll
        for (int mt = 0; mt < 4; ++mt)
            #pragma unroll
            for (int nt = 0; nt < 4; ++nt)
                acc[mt][nt] = __builtin_amdgcn_mfma_f32_16x16x32_bf16(af[mt], bfr[nt], acc[mt][nt], 0, 0, 0);
        if (c < 7) {                      // convert + stage after MFMA burst
            *reinterpret_cast<short8*>(&smem[(1 - cb) * ABUF + lO0]) = cvt8(a00, a01, ssA0);
            *reinterpret_cast<short8*>(&smem[(1 - cb) * ABUF + lO1]) = cvt8(a10, a11, ssA1);
            *reinterpret_cast<short8*>(&smem[(3 - cb) * ABUF + lO0]) = cvt8(b00, b01, ssB0);
            *reinterpret_cast<short8*>(&smem[(3 - cb) * ABUF + lO1]) = cvt8(b10, b11, ssB1);
            __syncthreads();
        }
    }

    // Row-norm reduction across the 4 quarter-lanes (tid bits 0-1).
    ssA0 += __shfl_xor(ssA0, 1); ssA0 += __shfl_xor(ssA0, 2);
    ssA1 += __shfl_xor(ssA1, 1); ssA1 += __shfl_xor(ssA1, 2);
    ssB0 += __shfl_xor(ssB0, 1); ssB0 += __shfl_xor(ssB0, 2);
    ssB1 += __shfl_xor(ssB1, 1); ssB1 += __shfl_xor(ssB1, 2);
    if (sq == 0) {
        nAs[srow] = ssA0; nAs[srow + 64] = ssA1;
        nBs[srow] = ssB0; nBs[srow + 64] = ssB1;
    }
    __syncthreads();                      // norms ready AND all LDS reads done

    // Epilogue: fragments (C/D col=lane&15, row=quad*4+reg, m89-verified)
    // -> LDS transpose tile -> 256B-contiguous column-segment stores.
    #pragma unroll
    for (int mt = 0; mt < 4; ++mt) {
        const int il = wr * 64 + mt * 16 + quad * 4;
        const float4 nv = *reinterpret_cast<const float4*>(&nAs[il]);
        #pragma unroll
        for (int nt = 0; nt < 4; ++nt) {
            const int jl = wc * 64 + nt * 16 + l16;
            const float y2 = nBs[jl];
            ushort4 pk;
            pk.x = f2bf(nv.x + y2 - 2.0f * acc[mt][nt][0]);
            pk.y = f2bf(nv.y + y2 - 2.0f * acc[mt][nt][1]);
            pk.z = f2bf(nv.z + y2 - 2.0f * acc[mt][nt][2]);
            pk.w = f2bf(nv.w + y2 - 2.0f * acc[mt][nt][3]);
            *reinterpret_cast<ushort4*>(&smem[jl * TST + il]) = pk;
        }
    }
    __syncthreads();
    const int rj = tid >> 4;              // 0..15
    const int rl = tid & 15;              // 0..15
    #pragma unroll
    for (int it = 0; it < 8; ++it) {
        const int jl = it * 16 + rj;
        short8 vrow = *reinterpret_cast<const short8*>(&smem[jl * TST + rl * 8]);
        *reinterpret_cast<short8*>(Dmat + (size_t)(j0base + jl) * 512 + i0base + rl * 8) = vrow;
    }
}

// ---- Kernel 2: one-wave hardmin DTW, 8x8 macro-steps ----------------------
// grid 192 x 64 threads (one wave). Lane t owns rows [8t, 8t+8).
// Macro-step m: lane t processes column block c = m - t (cols [8c, 8c+8)).
// Exchange: 8 pipelined shfl_up of lane t-1's bottom-row bots (its block c,
// computed at macro m-1). 127 macro-steps, depth-2 block prefetch.
__global__ __launch_bounds__(64, 1) void dtw_wave_kernel(
    const unsigned short* __restrict__ Dws, float* __restrict__ out) {
    const int z = blockIdx.x;            // 3*b + p
    const int b = z / 3;
    const int p = z - 3 * b;
    const unsigned short* Dmat = Dws + (size_t)z * 262144;   // col-major
    const int t = threadIdx.x;           // lane 0..63

    float prev[8];                        // R[8t+1..8t+8, j] of last done col
    #pragma unroll
    for (int r = 0; r < 8; ++r) prev[r] = SDTW_BIG;
    float bot8[8];                        // my row-(8t+8) values, last block
    #pragma unroll
    for (int i = 0; i < 8; ++i) bot8[i] = SDTW_BIG;
    float corner = SDTW_BIG;              // lane t-1 bot at col 8c-1

    const uint4* Dcol = reinterpret_cast<const uint4*>(Dmat) + t;  // + j*64

    uint4 cur[8], nxt[8];
    #pragma unroll
    for (int i = 0; i < 8; ++i) {         // block c = -t (clamped; real for t=0)
        const int j = -8 * t + i;
        const int jc = j < 0 ? 0 : (j > 511 ? 511 : j);
        cur[i] = Dcol[(size_t)jc * 64];
    }
    #pragma unroll
    for (int i = 0; i < 8; ++i) {         // block c = 1-t
        const int j = 8 * (1 - t) + i;
        const int jc = j < 0 ? 0 : (j > 511 ? 511 : j);
        nxt[i] = Dcol[(size_t)jc * 64];
    }

    for (int m = 0; m < 127; ++m) {
        const int c = m - t;
        // prefetch block c+2 (consumed 2 macro-steps from now)
        uint4 fut[8];
        #pragma unroll
        for (int i = 0; i < 8; ++i) {
            const int j = 8 * (c + 2) + i;
            const int jc = j < 0 ? 0 : (j > 511 ? 511 : j);
            fut[i] = Dcol[(size_t)jc * 64];
        }
        // exchange: 8 back-to-back shfls, one wait (amortized bpermute latency)
        float recv[8];
        #pragma unroll
        for (int i = 0; i < 8; ++i) recv[i] = __shfl_up(bot8[i], 1);

        if (c >= 0 && c < 64) {
            float u1[8], u0[8];           // up / diag seeds per column
            #pragma unroll
            for (int i = 0; i < 8; ++i) u1[i] = recv[i];
            u0[0] = corner;
            #pragma unroll
            for (int i = 1; i < 8; ++i) u0[i] = recv[i - 1];
            if (t == 0) {
                #pragma unroll
                for (int i = 0; i < 8; ++i) { u1[i] = SDTW_BIG; u0[i] = SDTW_BIG; }
                if (c == 0) u0[0] = 0.0f;  // R[0,0]
            } else if (c == 0) {
                u0[0] = SDTW_BIG;          // R[8t, -1]
            }
            #pragma unroll
            for (int i = 0; i < 8; ++i) {  // column j = 8c + i
                float d[8];
                d[0] = bf2f_lo(cur[i].x); d[1] = bf2f_hi(cur[i].x);
                d[2] = bf2f_lo(cur[i].y); d[3] = bf2f_hi(cur[i].y);
                d[4] = bf2f_lo(cur[i].z); d[5] = bf2f_hi(cur[i].z);
                d[6] = bf2f_lo(cur[i].w); d[7] = bf2f_hi(cur[i].w);
                float cc = d[0] + fminf(fminf(u0[i], prev[0]), u1[i]);
                float nv[8]; nv[0] = cc;
                #pragma unroll
                for (int r = 1; r < 8; ++r) {
                    cc = d[r] + fminf(fminf(prev[r - 1], prev[r]), cc);
                    nv[r] = cc;
                }
                #pragma unroll
                for (int r = 0; r < 8; ++r) prev[r] = nv[r];
                bot8[i] = cc;
            }
            corner = recv[7];
        }
        #pragma unroll
        for (int i = 0; i < 8; ++i) { cur[i] = nxt[i]; nxt[i] = fut[i]; }
    }

    if (t == 63) {                // bot8[7] == R[512,512]
        const float coef = (p == 0) ? 1.0f : -0.5f;
        atomicAdd(&out[b], coef * bot8[7]);
    }
}

extern "C" void kernel_launch(void* const* d_in, const int* in_sizes, int n_in,
                              void* d_out, int out_size, void* d_ws, size_t ws_size,
                              hipStream_t stream) {
    const float* x = (const float*)d_in[0];
    const float* y = (const float*)d_in[1];
    float* out = (float*)d_out;

    // ws layout: [0, 100663296) D bf16, 192 matrices x 262144 elems (col-major)
    unsigned short* Dws = (unsigned short*)d_ws;

    gemm_fused_kernel<<<dim3(4, 4, 192), 256, 0, stream>>>(x, y, Dws, out);
    dtw_wave_kernel<<<192, 64, 0, stream>>>(Dws, out);
}